// Round 8
// baseline (93.162 us; speedup 1.0000x reference)
//
#include <hip/hip_runtime.h>

#define BLK 256            // threads per block (4 waves)
#define LS  32             // timesteps per thread-chunk
#define SPB (BLK*LS)       // timesteps per block = 8192
#define STR (LS+1)         // plane stride 33: bank=(t+j)%32 -> <=2-way (free on CDNA4)

// shared-constant layout: M 16 | N 8 | SK 8*16 | GK 8*16
#define WC_M   0
#define WC_N   16
#define WC_SK  24
#define WC_GK  152
#define WC_TOT 280

// workspace layout (floats):
//   [0,    1024)  agg  = 256 float4   (block aggregates, k1 -> k2)
//   [1024, 2048)  xbs  = 256 float4   (block-start states, k2 -> k3)
//   [2048, 2328)  wsc  = C constants  (k1 block 0 -> k2,k3)
//   [4096, ... )  incl = 62720 float4 (per-thread wave-inclusive states, k1 -> k3)
#define WS_AGG_F32  0
#define WS_XBS_F32  1024
#define WS_C_F32    2048
#define WS_INCL_F32 4096

// ---------- affine step macro (row-major M[16], N[8]) ----------
#define STEP4(Mx,Nx, s0,s1,s2,s3, ux,uy, n0,n1,n2,n3)                                              \
  n0 = fmaf(Mx[0],s0,  fmaf(Mx[1],s1,  fmaf(Mx[2],s2,  fmaf(Mx[3],s3,  fmaf(Nx[0],ux, Nx[1]*uy))))); \
  n1 = fmaf(Mx[4],s0,  fmaf(Mx[5],s1,  fmaf(Mx[6],s2,  fmaf(Mx[7],s3,  fmaf(Nx[2],ux, Nx[3]*uy))))); \
  n2 = fmaf(Mx[8],s0,  fmaf(Mx[9],s1,  fmaf(Mx[10],s2, fmaf(Mx[11],s3, fmaf(Nx[4],ux, Nx[5]*uy))))); \
  n3 = fmaf(Mx[12],s0, fmaf(Mx[13],s1, fmaf(Mx[14],s2, fmaf(Mx[15],s3, fmaf(Nx[6],ux, Nx[7]*uy)))));

__device__ __forceinline__ float4 aff_apply(const float* Mx, float4 l, float4 c) {
  float4 r;
  r.x = fmaf(Mx[0],l.x,  fmaf(Mx[1],l.y,  fmaf(Mx[2],l.z,  fmaf(Mx[3],l.w,  c.x))));
  r.y = fmaf(Mx[4],l.x,  fmaf(Mx[5],l.y,  fmaf(Mx[6],l.z,  fmaf(Mx[7],l.w,  c.y))));
  r.z = fmaf(Mx[8],l.x,  fmaf(Mx[9],l.y,  fmaf(Mx[10],l.z, fmaf(Mx[11],l.w, c.z))));
  r.w = fmaf(Mx[12],l.x, fmaf(Mx[13],l.y, fmaf(Mx[14],l.z, fmaf(Mx[15],l.w, c.w))));
  return r;
}

__device__ __forceinline__ float4 matvec(const float* Mx, float4 v) {
  return aff_apply(Mx, v, make_float4(0.f, 0.f, 0.f, 0.f));
}

__device__ __forceinline__ float4 shfl_up4(float4 v, int d) {
  return make_float4(__shfl_up(v.x, d, 64), __shfl_up(v.y, d, 64),
                     __shfl_up(v.z, d, 64), __shfl_up(v.w, d, 64));
}

// ---------- wave-parallel fp64 constant builder (lane (i,j) owns element (i,j)) ----------
__device__ __forceinline__ double mm_el(double x, double y, int i, int j) {
  double s = 0.0;
  #pragma unroll
  for (int l = 0; l < 4; ++l)
    s = fma(__shfl(x, 4*i + l, 64), __shfl(y, 4*l + j, 64), s);
  return s;
}

__device__ __forceinline__ void wave_setup(const float* __restrict__ cin,
                                           const float* __restrict__ min_,
                                           const float* __restrict__ kin,
                                           const float* __restrict__ dtin,
                                           float* C, int lane) {
  double c1 = cin[0], c2 = cin[1], c3 = cin[2];
  double m1 = min_[0], m2 = min_[1];
  double k1 = kin[0], k2 = kin[1], k3 = kin[2];
  double h  = dtin[0];
  const int i = (lane >> 2) & 3, j = lane & 3;

  double a;
  if (i == 0)      a = (j == 1) ? 1.0 : 0.0;
  else if (i == 2) a = (j == 3) ? 1.0 : 0.0;
  else if (i == 1) a = (j==0) ? -(k1+k2)/m1 : (j==1) ? -(c1+c2)/m1
                     : (j==2) ?  k2/m1      :  c2/m1;
  else             a = (j==0) ?  k2/m2      : (j==1) ?  c2/m2
                     : (j==2) ? -(k3+k2)/m2 : -(c3+c2)/m2;

  const double id = (i == j) ? 1.0 : 0.0;
  double q  = id + (h/4.0)*a;
  double t  = mm_el(a, q,  i, j);
  double r  = id + (h/3.0)*t;
  t         = mm_el(a, r,  i, j);
  double s_ = id + (h/2.0)*t;
  t         = mm_el(a, s_, i, j);
  double m  = id + h*t;
  if (lane < 16) C[WC_M + lane] = (float)m;

  {
    int e = lane & 7, ii = e >> 1, jp = e & 1, col = jp ? 3 : 1;
    double sv = __shfl(s_, 4*ii + col, 64);
    double nv = h * sv / (jp ? m2 : m1);
    if (lane < 8) C[WC_N + lane] = (float)nv;
  }

  // SK[k] = M^(32*2^k), k=0..7 (M^32..M^4096); GK[k] = M^(8192*2^k), k=0..7
  double p = m;
  #pragma unroll
  for (int rr = 0; rr < 5; ++rr) p = mm_el(p, p, i, j);   // M^32
  if (lane < 16) C[WC_SK + lane] = (float)p;
  #pragma unroll
  for (int k = 1; k < 8; ++k) {
    p = mm_el(p, p, i, j);
    if (lane < 16) C[WC_SK + 16*k + lane] = (float)p;
  }
  p = mm_el(p, p, i, j);              // M^8192
  if (lane < 16) C[WC_GK + lane] = (float)p;
  #pragma unroll
  for (int k = 1; k < 8; ++k) {
    p = mm_el(p, p, i, j);
    if (lane < 16) C[WC_GK + 16*k + lane] = (float)p;
  }
}

// Wave-level inclusive affine scan over 64 chunk offsets (no barriers).
__device__ __forceinline__ float4 wave_scan(const float* SK, float4 b, int lane) {
  float4 cur = b;
  #pragma unroll
  for (int k = 0; k < 6; ++k) {
    int off = 1 << k;
    float4 l  = shfl_up4(cur, off);
    float4 nv = aff_apply(&SK[16*k], l, cur);
    if (lane >= off) cur = nv;
  }
  return cur;
}

// Cross-wave exclusive offset E_w = composed offset of waves 0..w-1 (each 2048 steps).
__device__ __forceinline__ float4 cross_wave_excl(const float* SK, const float4* Wagg, int w) {
  float4 E = make_float4(0.f, 0.f, 0.f, 0.f);
  if (w > 0) {
    E = Wagg[0];
    for (int q = 1; q < w; ++q) E = aff_apply(&SK[16*6], E, Wagg[q]);  // SK6 = M^2048
  }
  return E;
}

// ================= k1: stage + chunk + wave scan; emit incl[] and agg[] =================
// Diagnostic split (r8): no barrier, no atomics. Three rocprof rows localize the
// invariant ~40us that survived r0-r7 (two-pass == fused == all barrier designs).
__launch_bounds__(BLK)
__global__ void k_pass1(const float4* __restrict__ u4,
                        const float* __restrict__ cc, const float* __restrict__ mmp,
                        const float* __restrict__ kp, const float* __restrict__ dtp,
                        float4* __restrict__ agg, float* __restrict__ wsc,
                        float4* __restrict__ incl4, int T2) {
  __shared__ float  uxp[BLK*STR];
  __shared__ float  uyp[BLK*STR];
  __shared__ float  C[WC_TOT];
  __shared__ float4 Wagg[4];
  const int tid   = threadIdx.x;
  const int bid   = blockIdx.x;
  const int lane  = tid & 63, w = tid >> 6;
  const int base2 = bid * SPB;

  if (tid < 64) wave_setup(cc, mmp, kp, dtp, C, tid);

  // stage u: 16 float4/thread in 2 batches of 8 (8 outstanding loads/lane)
  #pragma unroll
  for (int b = 0; b < 2; ++b) {
    float4 vbuf[8];
    #pragma unroll
    for (int q = 0; q < 8; ++q) {
      int idx4 = tid + (b*8 + q)*BLK;
      float4 v = make_float4(0.f, 0.f, 0.f, 0.f);
      if (base2 + 2*idx4 < T2) v = u4[(base2 >> 1) + idx4];
      vbuf[q] = v;
    }
    #pragma unroll
    for (int q = 0; q < 8; ++q) {
      int idx4 = tid + (b*8 + q)*BLK;
      int s0 = 2*idx4;
      int t0 = s0 >> 5, j0 = s0 & 31;
      uxp[t0*STR + j0]   = vbuf[q].x;  uyp[t0*STR + j0]   = vbuf[q].y;
      uxp[t0*STR + j0+1] = vbuf[q].z;  uyp[t0*STR + j0+1] = vbuf[q].w;
    }
  }
  __syncthreads();

  // block 0 publishes constants for k2/k3
  if (bid == 0)
    for (int i = tid; i < WC_TOT; i += BLK) wsc[i] = C[i];

  float Mm[16], Nn[8];
  #pragma unroll
  for (int i = 0; i < 16; ++i) Mm[i] = C[WC_M+i];
  #pragma unroll
  for (int i = 0; i < 8;  ++i) Nn[i] = C[WC_N+i];
  const float* SK = &C[WC_SK];

  float b0 = 0.f, b1 = 0.f, b2 = 0.f, b3 = 0.f;
  #pragma unroll
  for (int j = 0; j < LS; ++j) {
    float ux = uxp[tid*STR + j], uy = uyp[tid*STR + j];
    float n0, n1, n2, n3;
    STEP4(Mm, Nn, b0, b1, b2, b3, ux, uy, n0, n1, n2, n3);
    b0 = n0; b1 = n1; b2 = n2; b3 = n3;
  }

  float4 incl = wave_scan(SK, make_float4(b0, b1, b2, b3), lane);
  incl4[bid*BLK + tid] = incl;               // 1 MB total, coalesced
  if (lane == 63) Wagg[w] = incl;
  __syncthreads();

  if (tid == BLK-1) {
    float4 E  = cross_wave_excl(SK, Wagg, 3);
    float4 t_ = matvec(&SK[16*6], E);        // SK6 = M^2048
    agg[bid] = make_float4(incl.x + t_.x, incl.y + t_.y, incl.z + t_.z, incl.w + t_.w);
  }
}

// ================= k2: single-block mid scan over [x0, agg...] -> xbs[] =================
__launch_bounds__(BLK)
__global__ void k_mid(const float4* __restrict__ agg, const float* __restrict__ wsc,
                      const float* __restrict__ x0in, float4* __restrict__ xbs,
                      int nblk) {
  __shared__ float4 MA[256];
  __shared__ float4 MB[256];
  __shared__ float  GKs[128];
  const int tid = threadIdx.x;
  const int n = nblk + 1;

  if (tid < 128) GKs[tid] = wsc[WC_GK + tid];
  if (tid < n) MA[tid] = (tid == 0) ? make_float4(x0in[0], x0in[1], x0in[2], x0in[3])
                                    : agg[tid-1];
  __syncthreads();

  float4* Aa = MA; float4* Bb = MB;
  for (int k = 0; k < 8; ++k) {
    int off = 1 << k;
    if (off >= n) break;
    if (tid < n) {
      float4 v = Aa[tid];
      if (tid >= off) v = aff_apply(&GKs[16*k], Aa[tid-off], v);
      Bb[tid] = v;
    }
    __syncthreads();
    float4* t = Aa; Aa = Bb; Bb = t;
  }
  if (tid < n) xbs[tid] = Aa[tid];           // state at start of block tid
}

// ================= k3: stage + lane start from incl/xbs + replay + writeout =============
__launch_bounds__(BLK)
__global__ void k_pass3(const float4* __restrict__ u4,
                        const float* __restrict__ wsc,
                        const float4* __restrict__ incl4,
                        const float4* __restrict__ xbs,
                        float4* __restrict__ out4, int T2) {
  __shared__ float  uxp[BLK*STR];
  __shared__ float  uyp[BLK*STR];
  __shared__ float  C[WC_TOT];
  __shared__ float4 WaggS[4];
  const int tid   = threadIdx.x;
  const int bid   = blockIdx.x;
  const int lane  = tid & 63, w = tid >> 6;
  const int base2 = bid * SPB;
  const int gid   = bid*BLK + tid;

  // independent loads up front: constants, wave aggregates, exclusive prefix
  for (int i = tid; i < WC_TOT; i += BLK) C[i] = wsc[i];
  if (tid < 4) WaggS[tid] = incl4[bid*BLK + tid*64 + 63];
  float4 ex = (lane == 0) ? make_float4(0.f, 0.f, 0.f, 0.f) : incl4[gid-1];

  // stage u (same pattern as k1)
  #pragma unroll
  for (int b = 0; b < 2; ++b) {
    float4 vbuf[8];
    #pragma unroll
    for (int q = 0; q < 8; ++q) {
      int idx4 = tid + (b*8 + q)*BLK;
      float4 v = make_float4(0.f, 0.f, 0.f, 0.f);
      if (base2 + 2*idx4 < T2) v = u4[(base2 >> 1) + idx4];
      vbuf[q] = v;
    }
    #pragma unroll
    for (int q = 0; q < 8; ++q) {
      int idx4 = tid + (b*8 + q)*BLK;
      int s0 = 2*idx4;
      int t0 = s0 >> 5, j0 = s0 & 31;
      uxp[t0*STR + j0]   = vbuf[q].x;  uyp[t0*STR + j0]   = vbuf[q].y;
      uxp[t0*STR + j0+1] = vbuf[q].z;  uyp[t0*STR + j0+1] = vbuf[q].w;
    }
  }
  __syncthreads();

  float Mm[16], Nn[8];
  #pragma unroll
  for (int i = 0; i < 16; ++i) Mm[i] = C[WC_M+i];
  #pragma unroll
  for (int i = 0; i < 8;  ++i) Nn[i] = C[WC_N+i];
  const float* SK = &C[WC_SK];

  // wave-start state: X_w = M^(2048*w)*Xbs + E_w
  float4 E  = cross_wave_excl(SK, WaggS, w);
  float4 Xw = xbs[bid];
  if (w & 1) Xw = matvec(&SK[16*6], Xw);      // M^2048
  if (w & 2) Xw = matvec(&SK[16*7], Xw);      // M^4096
  Xw = make_float4(Xw.x + E.x, Xw.y + E.y, Xw.z + E.z, Xw.w + E.w);

  // start = M^(32*lane)*X_w + ex
  float4 v = Xw;
  #pragma unroll
  for (int k = 0; k < 6; ++k)
    if (lane & (1 << k)) v = matvec(&SK[16*k], v);   // powers of M commute
  float x0 = v.x + ex.x, x1 = v.y + ex.y, x2 = v.z + ex.z, x3 = v.w + ex.w;

  // replay LS steps, write (z1,z2) back over consumed planes
  #pragma unroll
  for (int j = 0; j < LS; ++j) {
    float ux = uxp[tid*STR + j], uy = uyp[tid*STR + j];
    float n0, n1, n2, n3;
    STEP4(Mm, Nn, x0, x1, x2, x3, ux, uy, n0, n1, n2, n3);
    x0 = n0; x1 = n1; x2 = n2; x3 = n3;
    uxp[tid*STR + j] = x0;   // z1
    uyp[tid*STR + j] = x2;   // z2
  }
  __syncthreads();

  // coalesced writeout: each float4 = 2 timesteps of (z1,z2)
  #pragma unroll
  for (int kk = 0; kk < SPB/2/BLK; ++kk) {
    int idx4 = tid + kk*BLK;
    int s0 = 2*idx4;
    if (base2 + s0 < T2) {
      int t0 = s0 >> 5, j0 = s0 & 31;
      out4[(base2 >> 1) + idx4] = make_float4(uxp[t0*STR + j0],   uyp[t0*STR + j0],
                                              uxp[t0*STR + j0+1], uyp[t0*STR + j0+1]);
    }
  }
}

extern "C" void kernel_launch(void* const* d_in, const int* in_sizes, int n_in,
                              void* d_out, int out_size, void* d_ws, size_t ws_size,
                              hipStream_t stream) {
  const float4* u4  = (const float4*)d_in[0];
  const float*  x0  = (const float*)d_in[1];
  const float*  cc  = (const float*)d_in[2];
  const float*  mm  = (const float*)d_in[3];
  const float*  kk  = (const float*)d_in[4];
  const float*  dt  = (const float*)d_in[5];

  int T2   = in_sizes[0] / 2;                  // timesteps
  int nblk = (T2 + SPB - 1) / SPB;             // 245 for T=2e6; nblk+1 <= 256 required

  float*  ws    = (float*)d_ws;
  float4* agg   = (float4*)(ws + WS_AGG_F32);
  float4* xbs   = (float4*)(ws + WS_XBS_F32);
  float*  wsc   = ws + WS_C_F32;
  float4* incl4 = (float4*)(ws + WS_INCL_F32);

  k_pass1<<<nblk, BLK, 0, stream>>>(u4, cc, mm, kk, dt, agg, wsc, incl4, T2);
  k_mid  <<<1,    BLK, 0, stream>>>(agg, wsc, x0, xbs, nblk);
  k_pass3<<<nblk, BLK, 0, stream>>>(u4, wsc, incl4, xbs, (float4*)d_out, T2);
}

// Round 9
// 90.330 us; speedup vs baseline: 1.0314x; 1.0314x over previous
//
#include <hip/hip_runtime.h>

#define BLK 256            // threads per block (4 waves)
#define LS  32             // timesteps per thread-chunk
#define SPB (BLK*LS)       // timesteps per block = 8192
#define STR (LS+1)         // plane stride 33: bank=(t+j)%32 -> <=2-way (free on CDNA4)

// shared-constant layout: M 16 | N 8 | SK 8*16 | GK 8*16
#define WC_M   0
#define WC_N   16
#define WC_SK  24
#define WC_GK  152
#define WC_TOT 280

// workspace layout (bytes): [0, 4096) agg = 256 float4;
// barrier region after it: arr[256] u32 (store-only arrivals), flag on own line.
#define WS_BAR_F32   1024        // float offset of barrier region (byte 4096)
#define BAR_ARR_U32  0
#define BAR_FLAG_U32 272         // byte +1088, line [1024,1152) -> separate from arr
#define BAR_BYTES    1152

typedef unsigned long long u64t;
union F2U { float2 f; u64t u; };

// ---------- affine step macro (row-major M[16], N[8]) ----------
#define STEP4(Mx,Nx, s0,s1,s2,s3, ux,uy, n0,n1,n2,n3)                                              \
  n0 = fmaf(Mx[0],s0,  fmaf(Mx[1],s1,  fmaf(Mx[2],s2,  fmaf(Mx[3],s3,  fmaf(Nx[0],ux, Nx[1]*uy))))); \
  n1 = fmaf(Mx[4],s0,  fmaf(Mx[5],s1,  fmaf(Mx[6],s2,  fmaf(Mx[7],s3,  fmaf(Nx[2],ux, Nx[3]*uy))))); \
  n2 = fmaf(Mx[8],s0,  fmaf(Mx[9],s1,  fmaf(Mx[10],s2, fmaf(Mx[11],s3, fmaf(Nx[4],ux, Nx[5]*uy))))); \
  n3 = fmaf(Mx[12],s0, fmaf(Mx[13],s1, fmaf(Mx[14],s2, fmaf(Mx[15],s3, fmaf(Nx[6],ux, Nx[7]*uy)))));

__device__ __forceinline__ float4 aff_apply(const float* Mx, float4 l, float4 c) {
  float4 r;
  r.x = fmaf(Mx[0],l.x,  fmaf(Mx[1],l.y,  fmaf(Mx[2],l.z,  fmaf(Mx[3],l.w,  c.x))));
  r.y = fmaf(Mx[4],l.x,  fmaf(Mx[5],l.y,  fmaf(Mx[6],l.z,  fmaf(Mx[7],l.w,  c.y))));
  r.z = fmaf(Mx[8],l.x,  fmaf(Mx[9],l.y,  fmaf(Mx[10],l.z, fmaf(Mx[11],l.w, c.z))));
  r.w = fmaf(Mx[12],l.x, fmaf(Mx[13],l.y, fmaf(Mx[14],l.z, fmaf(Mx[15],l.w, c.w))));
  return r;
}

__device__ __forceinline__ float4 matvec(const float* Mx, float4 v) {
  return aff_apply(Mx, v, make_float4(0.f, 0.f, 0.f, 0.f));
}

__device__ __forceinline__ float4 shfl_up4(float4 v, int d) {
  return make_float4(__shfl_up(v.x, d, 64), __shfl_up(v.y, d, 64),
                     __shfl_up(v.z, d, 64), __shfl_up(v.w, d, 64));
}

// ---------- wave-parallel fp64 constant builder (lane (i,j) owns element (i,j)) ----------
__device__ __forceinline__ double mm_el(double x, double y, int i, int j) {
  double s = 0.0;
  #pragma unroll
  for (int l = 0; l < 4; ++l)
    s = fma(__shfl(x, 4*i + l, 64), __shfl(y, 4*l + j, 64), s);
  return s;
}

__device__ __forceinline__ void wave_setup(const float* __restrict__ cin,
                                           const float* __restrict__ min_,
                                           const float* __restrict__ kin,
                                           const float* __restrict__ dtin,
                                           float* C, int lane) {
  double c1 = cin[0], c2 = cin[1], c3 = cin[2];
  double m1 = min_[0], m2 = min_[1];
  double k1 = kin[0], k2 = kin[1], k3 = kin[2];
  double h  = dtin[0];
  const int i = (lane >> 2) & 3, j = lane & 3;

  double a;
  if (i == 0)      a = (j == 1) ? 1.0 : 0.0;
  else if (i == 2) a = (j == 3) ? 1.0 : 0.0;
  else if (i == 1) a = (j==0) ? -(k1+k2)/m1 : (j==1) ? -(c1+c2)/m1
                     : (j==2) ?  k2/m1      :  c2/m1;
  else             a = (j==0) ?  k2/m2      : (j==1) ?  c2/m2
                     : (j==2) ? -(k3+k2)/m2 : -(c3+c2)/m2;

  const double id = (i == j) ? 1.0 : 0.0;
  double q  = id + (h/4.0)*a;
  double t  = mm_el(a, q,  i, j);
  double r  = id + (h/3.0)*t;
  t         = mm_el(a, r,  i, j);
  double s_ = id + (h/2.0)*t;
  t         = mm_el(a, s_, i, j);
  double m  = id + h*t;
  if (lane < 16) C[WC_M + lane] = (float)m;

  {
    int e = lane & 7, ii = e >> 1, jp = e & 1, col = jp ? 3 : 1;
    double sv = __shfl(s_, 4*ii + col, 64);
    double nv = h * sv / (jp ? m2 : m1);
    if (lane < 8) C[WC_N + lane] = (float)nv;
  }

  // SK[k] = M^(32*2^k), k=0..7 (M^32..M^4096); GK[k] = M^(8192*2^k), k=0..7
  double p = m;
  #pragma unroll
  for (int rr = 0; rr < 5; ++rr) p = mm_el(p, p, i, j);   // M^32
  if (lane < 16) C[WC_SK + lane] = (float)p;
  #pragma unroll
  for (int k = 1; k < 8; ++k) {
    p = mm_el(p, p, i, j);
    if (lane < 16) C[WC_SK + 16*k + lane] = (float)p;
  }
  p = mm_el(p, p, i, j);              // M^8192
  if (lane < 16) C[WC_GK + lane] = (float)p;
  #pragma unroll
  for (int k = 1; k < 8; ++k) {
    p = mm_el(p, p, i, j);
    if (lane < 16) C[WC_GK + 16*k + lane] = (float)p;
  }
}

// Wave-level inclusive affine scan over 64 chunk offsets (no barriers).
__device__ __forceinline__ float4 wave_scan(const float* SK, float4 b, int lane) {
  float4 cur = b;
  #pragma unroll
  for (int k = 0; k < 6; ++k) {
    int off = 1 << k;
    float4 l  = shfl_up4(cur, off);
    float4 nv = aff_apply(&SK[16*k], l, cur);
    if (lane >= off) cur = nv;
  }
  return cur;
}

// Cross-wave exclusive offset E_w = composed offset of waves 0..w-1 (each 2048 steps).
__device__ __forceinline__ float4 cross_wave_excl(const float* SK, const float4* Wagg, int w) {
  float4 E = make_float4(0.f, 0.f, 0.f, 0.f);
  if (w > 0) {
    E = Wagg[0];
    for (int q = 1; q < w; ++q) E = aff_apply(&SK[16*6], E, Wagg[q]);  // SK6 = M^2048
  }
  return E;
}

// ---------- fused single-pass kernel (r9: I$-footprint reduction) ----------
// r8 post-mortem: sync design, WG count, staging ILP, kernel count ALL null;
// measured FETCH+WRITE ~24MB (~4us) and VALUBusy ~6.5% (~5us) cannot explain
// ~40us. Remaining unmodeled pipe: INSTRUCTION FETCH. All prior versions
// fully unrolled the STEP4 loops twice (~25-30KB straight-line text executed
// once per wave, cold 32KB I$ per CU, cold L2 after the 268MB poison fill).
// Fix: #pragma unroll 4 on chunk/replay/writeout loops -> ~8x less text,
// I$-resident after the first loop iteration. Math identical to r7 (passed).
// LDS: 2*33792 + 2*4096 + 1120 + 64 = 76864 B -> 2 blocks/CU; launch_bounds(256,2).
// Deadlock-safety: 245 blocks <= 512 resident slots. Barrier: store-only
// arrivals + block-0 sweep (ordering argument proven r4-r7).
__launch_bounds__(BLK, 2)
__global__ void k_fused(const float4* __restrict__ u4,
                        const float* __restrict__ cc, const float* __restrict__ mmp,
                        const float* __restrict__ kp, const float* __restrict__ dtp,
                        float4* __restrict__ agg, unsigned* __restrict__ bar,
                        const float* __restrict__ x0in, float4* __restrict__ out4,
                        int T2, int nblk) {
  __shared__ float  uxp[BLK*STR];
  __shared__ float  uyp[BLK*STR];
  __shared__ float4 MA[256];
  __shared__ float4 MB[256];
  __shared__ float  C[WC_TOT];
  __shared__ float4 Wagg[4];
  const int tid   = threadIdx.x;
  const int bid   = blockIdx.x;
  const int lane  = tid & 63, w = tid >> 6;
  const int base2 = bid * SPB;

  // wave 0 builds all constants in fp64 while waves 1-3 stage u
  if (tid < 64) wave_setup(cc, mmp, kp, dtp, C, tid);

  // stage u: 16 float4/thread in 2 batches of 8 (8 outstanding loads/lane)
  #pragma unroll
  for (int b = 0; b < 2; ++b) {
    float4 vbuf[8];
    #pragma unroll
    for (int q = 0; q < 8; ++q) {
      int idx4 = tid + (b*8 + q)*BLK;
      float4 v = make_float4(0.f, 0.f, 0.f, 0.f);
      if (base2 + 2*idx4 < T2) v = u4[(base2 >> 1) + idx4];
      vbuf[q] = v;
    }
    #pragma unroll
    for (int q = 0; q < 8; ++q) {
      int idx4 = tid + (b*8 + q)*BLK;
      int s0 = 2*idx4;
      int t0 = s0 >> 5, j0 = s0 & 31;
      uxp[t0*STR + j0]   = vbuf[q].x;  uyp[t0*STR + j0]   = vbuf[q].y;
      uxp[t0*STR + j0+1] = vbuf[q].z;  uyp[t0*STR + j0+1] = vbuf[q].w;
    }
  }
  __syncthreads();

  float Mm[16], Nn[8];
  #pragma unroll
  for (int i = 0; i < 16; ++i) Mm[i] = C[WC_M+i];
  #pragma unroll
  for (int i = 0; i < 8;  ++i) Nn[i] = C[WC_N+i];
  const float* SK = &C[WC_SK];
  const float* GK = &C[WC_GK];

  // per-thread chunk offset over LS steps from zero state (partial unroll: small text)
  float b0 = 0.f, b1 = 0.f, b2 = 0.f, b3 = 0.f;
  #pragma unroll 4
  for (int j = 0; j < LS; ++j) {
    float ux = uxp[tid*STR + j], uy = uyp[tid*STR + j];
    float n0, n1, n2, n3;
    STEP4(Mm, Nn, b0, b1, b2, b3, ux, uy, n0, n1, n2, n3);
    b0 = n0; b1 = n1; b2 = n2; b3 = n3;
  }

  float4 incl = wave_scan(SK, make_float4(b0, b1, b2, b3), lane);
  if (lane == 63) Wagg[w] = incl;
  __syncthreads();

  // ---- publish block aggregate (store-only arrival) ----
  if (tid == BLK-1) {
    float4 E = cross_wave_excl(SK, Wagg, 3);
    float4 t_ = matvec(&SK[16*6], E);      // SK6 = M^2048
    F2U lo, hi;
    lo.f = make_float2(incl.x + t_.x, incl.y + t_.y);
    hi.f = make_float2(incl.z + t_.z, incl.w + t_.w);
    u64t* aggu = (u64t*)(agg + bid);
    __hip_atomic_store(aggu + 0, lo.u, __ATOMIC_RELAXED, __HIP_MEMORY_SCOPE_AGENT);
    __hip_atomic_store(aggu + 1, hi.u, __ATOMIC_RELAXED, __HIP_MEMORY_SCOPE_AGENT);
    asm volatile("s_waitcnt vmcnt(0)" ::: "memory");
    __hip_atomic_store(&bar[BAR_ARR_U32 + bid], 1u,
                       __ATOMIC_RELAXED, __HIP_MEMORY_SCOPE_AGENT);
  }

  // ---- grid barrier: block 0 wave 3 sweeps arrivals, others poll the flag ----
  if (bid == 0 && w == 3) {
    for (;;) {
      int ok = 1;
      #pragma unroll
      for (int it = 0; it < 4; ++it) {
        int i = lane + 64*it;
        unsigned v = __hip_atomic_load(&bar[BAR_ARR_U32 + i],
                                       __ATOMIC_RELAXED, __HIP_MEMORY_SCOPE_AGENT);
        ok &= (i >= nblk) | (v != 0u);
      }
      if (__all(ok)) break;
      __builtin_amdgcn_s_sleep(4);
    }
    if (lane == 63)
      __hip_atomic_store(&bar[BAR_FLAG_U32], 1u,
                         __ATOMIC_RELAXED, __HIP_MEMORY_SCOPE_AGENT);
  } else if (tid == BLK-1) {
    while (!__hip_atomic_load(&bar[BAR_FLAG_U32],
                              __ATOMIC_RELAXED, __HIP_MEMORY_SCOPE_AGENT))
      __builtin_amdgcn_s_sleep(8);
  }
  __syncthreads();     // block waits for its poller/sweeper wave

  // ---- mid scan over [x0, agg_0..agg_{nblk-1}] (n <= 256), plain cached loads ----
  const int n = nblk + 1;
  if (tid < n) MA[tid] = (tid == 0) ? make_float4(x0in[0], x0in[1], x0in[2], x0in[3])
                                    : agg[tid-1];
  __syncthreads();

  // ping-pong Hillis-Steele mid scan (8 rounds, 1 sync each)
  float4* Aa = MA; float4* Bb = MB;
  for (int k = 0; k < 8; ++k) {
    int off = 1 << k;
    if (off >= n) break;
    if (tid < n) {
      float4 v = Aa[tid];
      if (tid >= off) v = aff_apply(&GK[16*k], Aa[tid-off], v);
      Bb[tid] = v;
    }
    __syncthreads();
    float4* t = Aa; Aa = Bb; Bb = t;
  }

  float4 Xbs = Aa[bid];                       // state at start of this block

  // wave-start state: X_w = M^(2048*w)*Xbs + E_w
  float4 E  = cross_wave_excl(SK, Wagg, w);
  float4 Xw = Xbs;
  if (w & 1) Xw = matvec(&SK[16*6], Xw);      // M^2048
  if (w & 2) Xw = matvec(&SK[16*7], Xw);      // M^4096
  Xw = make_float4(Xw.x + E.x, Xw.y + E.y, Xw.z + E.z, Xw.w + E.w);

  // start = M^(32*lane)*X_w + (lane>0 ? incl[lane-1] : 0)
  float4 ex = shfl_up4(incl, 1);
  if (lane == 0) ex = make_float4(0.f, 0.f, 0.f, 0.f);
  float4 v = Xw;
  #pragma unroll
  for (int k = 0; k < 6; ++k)
    if (lane & (1 << k)) v = matvec(&SK[16*k], v);   // powers of M commute
  float x0 = v.x + ex.x, x1 = v.y + ex.y, x2 = v.z + ex.z, x3 = v.w + ex.w;

  // replay LS steps from still-staged u, write (z1,z2) back (partial unroll)
  #pragma unroll 4
  for (int j = 0; j < LS; ++j) {
    float ux = uxp[tid*STR + j], uy = uyp[tid*STR + j];
    float n0, n1, n2, n3;
    STEP4(Mm, Nn, x0, x1, x2, x3, ux, uy, n0, n1, n2, n3);
    x0 = n0; x1 = n1; x2 = n2; x3 = n3;
    uxp[tid*STR + j] = x0;   // z1
    uyp[tid*STR + j] = x2;   // z2
  }
  __syncthreads();

  // coalesced writeout: each float4 = 2 timesteps of (z1,z2) (partial unroll)
  #pragma unroll 4
  for (int kk = 0; kk < SPB/2/BLK; ++kk) {
    int idx4 = tid + kk*BLK;
    int s0 = 2*idx4;
    if (base2 + s0 < T2) {
      int t0 = s0 >> 5, j0 = s0 & 31;
      out4[(base2 >> 1) + idx4] = make_float4(uxp[t0*STR + j0],   uyp[t0*STR + j0],
                                              uxp[t0*STR + j0+1], uyp[t0*STR + j0+1]);
    }
  }
}

extern "C" void kernel_launch(void* const* d_in, const int* in_sizes, int n_in,
                              void* d_out, int out_size, void* d_ws, size_t ws_size,
                              hipStream_t stream) {
  const float4* u4  = (const float4*)d_in[0];
  const float*  x0  = (const float*)d_in[1];
  const float*  cc  = (const float*)d_in[2];
  const float*  mm  = (const float*)d_in[3];
  const float*  kk  = (const float*)d_in[4];
  const float*  dt  = (const float*)d_in[5];

  int T2   = in_sizes[0] / 2;                  // timesteps
  int nblk = (T2 + SPB - 1) / SPB;             // 245 for T=2e6; nblk+1 <= 256 required

  float*    ws  = (float*)d_ws;
  float4*   agg = (float4*)ws;                 // 256 float4
  unsigned* bar = (unsigned*)(ws + WS_BAR_F32);

  // zero arrival words + flag (captured into the graph -> re-zeroed every replay)
  hipMemsetAsync((void*)bar, 0, BAR_BYTES, stream);

  k_fused<<<nblk, BLK, 0, stream>>>(u4, cc, mm, kk, dt, agg, bar, x0,
                                    (float4*)d_out, T2, nblk);
}